// Round 4
// baseline (192.383 us; speedup 1.0000x reference)
//
#include <hip/hip_runtime.h>

#define NP 81
#define CC 128
#define HH 128
#define WW 256
#define SX 24            // output x-strip width: 24+9-1 = 32 = ONE B tile
#define NXT 11           // ceil(256/24); last strip is 16 wide (predicated)
#define NBLK (NXT * 16 * 4)   // 704 blocks; 704 % 8 == 0 -> bijective XCD swizzle

typedef __attribute__((ext_vector_type(8))) short short8;
typedef __attribute__((ext_vector_type(4))) float f32x4;
typedef __attribute__((ext_vector_type(16))) float f32x16;

__device__ __forceinline__ short f2bf(float f) {
    unsigned int u = __builtin_bit_cast(unsigned int, f);
    u += 0x7fffu + ((u >> 16) & 1u);   // round-to-nearest-even
    return (short)(u >> 16);
}

// Fused cost volume. Block = (b, 24-x strip, 8-y strip), 16 waves.
// R4 restructure (R3 was latency-bound: all pipes <30%, issued reads at only
// ~40% of achievable BW): per-wave program was B-gather(64 lockstep loads) ->
// A-stage(24 loads) -> barrier -> memory-quiet compute. Now:
//   1. A-stage FIRST (only barrier dependency; 24 loads issue at t=0).
//   2. B-gather AFTER the barrier, software-pipelined depth-2 (16 raw f32
//      regs, static indexing): ~16 loads in flight per wave, counted vmcnt
//      waits instead of full drains; overlaps other waves' MFMA phase.
//   3. OOB lanes: clamped addresses + masked zeroing (branch-free pipe).
// Liveness peak ~52 VGPR (acc in AGPRs) -> stays in the 64-reg budget that
// keeps 2 blocks/CU (R1 lesson: >64 live => spill => +95 MB scratch).
__global__ __launch_bounds__(1024) void corr_fused24(
        const float* __restrict__ t1, const float* __restrict__ t2,
        float* __restrict__ out) {
    const int bid = blockIdx.x;
    const int sw  = (bid & 7) * (NBLK / 8) + (bid >> 3);  // XCD-contiguous
    const int ys = sw & 15;
    const int v  = sw >> 4;          // 0..43
    const int xt = v % NXT;
    const int b  = v / NXT;
    const int X0 = xt * SX;
    const int y0 = ys * 8;

    const int tid  = threadIdx.x;
    const int lane = tid & 63;
    const int w    = tid >> 6;        // 0..15: owns t2 row y0-4+w
    const int n    = lane & 31;       // MFMA A-row m / B-col n index
    const int g    = lane >> 5;       // k-group

    __shared__ short sA[8 * SX * 128];            // 48 KB, XOR-swizzled
    __shared__ __align__(16) float obufs[16 * 9 * 28];  // 15.75 KB

    const size_t plane = (size_t)HH * WW;
    const int r = y0 - 4 + w;                     // t2 row this wave owns

    // ---- stage A FIRST: t1 rows y0..y0+7, SX x, 128 c (shared by 16 waves)
#pragma unroll
    for (int i = 0; i < 3; ++i) {
        const int unit = tid + i * 1024;          // 3072 = 8y * 24x * 16oct
        const int x    = unit % SX;
        const int rest = unit / SX;               // 0..127
        const int oct  = rest & 15;
        const int yy   = rest >> 4;
        short8 pk = {0,0,0,0,0,0,0,0};
        if (X0 + x < WW) {
            const float* p = t1 + ((size_t)(b * CC + oct * 8) * HH + (y0 + yy)) * WW
                           + X0 + x;
#pragma unroll
            for (int j = 0; j < 8; ++j) pk[j] = f2bf(p[(size_t)j * plane]);
        }
        *(short8*)&sA[yy * (SX * 128) + x * 128 + ((oct ^ (x & 15)) * 8)] = pk;
    }
    __syncthreads();

    // ---- B gather, post-barrier, pipelined depth-2.
    // lane holds x2 = X0-4+n, c = kc*16 + g*8 + j (bf16x8 per kc)
    const int x2 = X0 - 4 + n;
    const bool ok = (r >= 0) && (r < HH) && (x2 >= 0) && (x2 < WW);
    const int rc  = r  < 0 ? 0 : (r  > HH - 1 ? HH - 1 : r);
    const int xc  = x2 < 0 ? 0 : (x2 > WW - 1 ? WW - 1 : x2);
    const float* bp = t2 + ((size_t)(b * CC + g * 8) * HH + rc) * WW + xc;

    short8 bre[8];
    {
        float r0[8], r1[8];
#pragma unroll
        for (int j = 0; j < 8; ++j) r0[j] = bp[(size_t)j * plane];          // kc0
#pragma unroll
        for (int j = 0; j < 8; ++j) r1[j] = bp[(size_t)(16 + j) * plane];   // kc1
#pragma unroll
        for (int kp = 0; kp < 4; ++kp) {
            const int kc0 = 2 * kp, kc1 = 2 * kp + 1;
            {
                short8 f;
#pragma unroll
                for (int j = 0; j < 8; ++j) f[j] = f2bf(r0[j]);
                if (!ok) f = (short8){0,0,0,0,0,0,0,0};
                bre[kc0] = f;
            }
            if (kp < 3) {
#pragma unroll
                for (int j = 0; j < 8; ++j)
                    r0[j] = bp[(size_t)((kc0 + 2) * 16 + j) * plane];
            }
            {
                short8 f;
#pragma unroll
                for (int j = 0; j < 8; ++j) f[j] = f2bf(r1[j]);
                if (!ok) f = (short8){0,0,0,0,0,0,0,0};
                bre[kc1] = f;
            }
            if (kp < 3) {
#pragma unroll
                for (int j = 0; j < 8; ++j)
                    r1[j] = bp[(size_t)((kc1 + 2) * 16 + j) * plane];
            }
        }
    }

    const int ylo = (w > 8) ? (w - 8) : 0;
    const int yhi = (w < 7) ? w : 7;
    float* ob = &obufs[w * 252];                  // [9 dj][28] f32, per wave

    for (int yy = ylo; yy <= yhi; ++yy) {
        const int sbase = yy * (SX * 128) + n * 128;

        f32x16 a;
#pragma unroll
        for (int q = 0; q < 16; ++q) a[q] = 0.f;
#pragma unroll
        for (int kc = 0; kc < 8; ++kc) {
            const short8 af = *(const short8*)
                &sA[sbase + (((kc * 2 + g) ^ (n & 15)) * 8)];
            a = __builtin_amdgcn_mfma_f32_32x32x16_bf16(af, bre[kc], a, 0, 0, 0);
        }

        // band extract: D(row m = x offset, col n) -> dj = n - m
#pragma unroll
        for (int q = 0; q < 16; ++q) {
            const int m  = (q & 3) + 8 * (q >> 2) + 4 * g;
            const int dj = n - m;
            if (dj >= 0 && dj <= 8 && m < SX) ob[dj * 28 + m] = a[q];
        }

        // coalesced stores: 9 dj rows x 24 x = 54 f32x4 (one round, lane<54)
        const int di = w - yy;
        const int y  = y0 + yy;
        if (lane < 54) {
            const int dj = lane / 6, xq = lane % 6;
            if (X0 + xq * 4 < WW) {
                f32x4 vv = *(const f32x4*)&ob[dj * 28 + xq * 4];
                *(f32x4*)&out[((size_t)(b * NP + di * 9 + dj) * HH + y) * WW
                              + X0 + xq * 4] = vv;
            }
        }
    }
}

extern "C" void kernel_launch(void* const* d_in, const int* in_sizes, int n_in,
                              void* d_out, int out_size, void* d_ws, size_t ws_size,
                              hipStream_t stream) {
    const float* t1 = (const float*)d_in[0];
    const float* t2 = (const float*)d_in[1];
    corr_fused24<<<NBLK, 1024, 0, stream>>>(t1, t2, (float*)d_out);
}